// Round 9
// baseline (161988.855 us; speedup 1.0000x reference)
//
#include <hip/hip_runtime.h>
#include <math.h>

#define T_STEPS 20000
#define RSIZE   2048
#define ISIZE   128
#define NBLK    64
#define NTHR    512                    // 8 waves/block, 1 block/CU
#define WPB     (NTHR / 64)            // 8 waves per block
#define NWAVE   (NBLK * WPB)           // 512 waves total
#define RPW     (RSIZE / NWAVE)        // 4 rows per wave

// ---- cheap erf: Abramowitz-Stegun 7.1.26, |err| <= 1.5e-7 (abs) ----
__device__ __forceinline__ float erf_approx(float x) {
    float ax = fabsf(x);
    float t  = 1.0f / (1.0f + 0.3275911f * ax);
    float y  = t * (0.254829592f +
               t * (-0.284496736f +
               t * (1.421413741f +
               t * (-1.453152027f +
               t * 1.061405429f))));
    float e  = __expf(-ax * ax);
    float r  = 1.0f - y * e;
    return copysignf(r, x);
}

// ---- AGPR parking (gfx950 unified RF; no MFMA here, AGPRs = free storage).
// VALU cannot source AGPRs on gfx950 — only v_accvgpr_read/write move data.
#define AGPR_W(a, v) asm volatile("v_accvgpr_write_b32 %0, %1" : "=a"(a) : "v"(v))
#define AGPR_R(v, a) asm volatile("v_accvgpr_read_b32 %0, %1" : "=v"(v) : "a"(a))

__device__ __forceinline__ void st_coh_f32(float* p, float v) {
    asm volatile("global_store_dword %0, %1, off sc0 sc1"
                 :: "v"(p), "v"(v) : "memory");
}
__device__ __forceinline__ void st_coh_u32(unsigned* p, unsigned v) {
    asm volatile("global_store_dword %0, %1, off sc0 sc1"
                 :: "v"(p), "v"(v) : "memory");
}

__global__ __launch_bounds__(NTHR, 2) void esn_persistent(
        const float* __restrict__ input,   // [T, 128]
        const float* __restrict__ W_in,    // [2048, 128]
        const float* __restrict__ W_res,   // [2048, 2048]
        float* __restrict__ out,           // [T, 2048] (rows ARE the states)
        unsigned* __restrict__ tags) {     // [2][512] per-wave monotonic tags
    const int tid  = threadIdx.x;
    const int lane = tid & 63;
    const int wv   = tid >> 6;
    const int wid  = blockIdx.x * WPB + wv;
    const int r0   = wid * RPW;
    const float invs = 0.022097086912079608f;  // 1/sqrt(2048)

    // ---- load W once, park in AGPRs (row r0+m, lane l: cols c*256+l*4..+3) --
    float a_w[RPW][32];
    float a_wi[RPW][2];
#pragma unroll
    for (int m = 0; m < RPW; ++m) {
        const float* row = W_res + (size_t)(r0 + m) * RSIZE;
#pragma unroll
        for (int c = 0; c < 8; ++c) {
            float4 w = *(const float4*)(row + c * 256 + lane * 4);
            AGPR_W(a_w[m][c * 4 + 0], w.x);
            AGPR_W(a_w[m][c * 4 + 1], w.y);
            AGPR_W(a_w[m][c * 4 + 2], w.z);
            AGPR_W(a_w[m][c * 4 + 3], w.w);
        }
        float2 wiv = *(const float2*)(W_in + (size_t)(r0 + m) * ISIZE + lane * 2);
        AGPR_W(a_wi[m][0], wiv.x);
        AGPR_W(a_wi[m][1], wiv.y);
    }

    for (int t = 0; t < T_STEPS; ++t) {
        // ---- input projection (independent of other waves) ----
        float2 uv = ((const float2*)(input + (size_t)t * ISIZE))[lane];
        float acc[RPW];
#pragma unroll
        for (int m = 0; m < RPW; ++m) {
            float w0, w1;
            AGPR_R(w0, a_wi[m][0]);
            AGPR_R(w1, a_wi[m][1]);
            acc[m] = fmaf(w0, uv.x, w1 * uv.y);
        }

        // ---- acquire x[t-1]: poll 512 per-wave tags, then gather from out --
        float4 xv[8];
        float  xp = 0.0f;
        if (t > 0) {
            const int s = (t - 1) & 1;
            const unsigned want = (unsigned)t;
            const unsigned* tp = tags + s * NWAVE + lane * 8;
            uint4 g0, g1;
            while (true) {
                // "=&v": early-clobber — outputs must NOT overlap the
                // address register while later loads are still unissued.
                asm volatile(
                    "global_load_dwordx4 %0, %2, off sc0 sc1\n\t"
                    "global_load_dwordx4 %1, %2, off offset:16 sc0 sc1\n\t"
                    "s_waitcnt vmcnt(0)"
                    : "=&v"(g0), "=&v"(g1) : "v"(tp) : "memory");
                __builtin_amdgcn_sched_barrier(0);
                bool ok = g0.x >= want && g0.y >= want &&
                          g0.z >= want && g0.w >= want &&
                          g1.x >= want && g1.y >= want &&
                          g1.z >= want && g1.w >= want;
                if (__all((int)ok)) break;
                __builtin_amdgcn_s_sleep(1);
            }
            // Tags observed => producers' coherent stores are at L3; our
            // sc0 sc1 loads are serviced at L3 => fresh. Row t-1 is written
            // exactly once, so no lap hazard on data.
            // 13-bit imm offset (max 4095 B): two base pointers.
            const float* xprev = out + (size_t)(t - 1) * RSIZE;
            const float* xb0 = xprev + lane * 4;            // bytes 0..3072
            const float* xb1 = xb0 + 1024;                  // bytes 4096..7168
            const float* xq  = xprev + r0 + (lane & 3);     // leak term
            asm volatile(
                "global_load_dwordx4 %0, %9, off sc0 sc1\n\t"
                "global_load_dwordx4 %1, %9, off offset:1024 sc0 sc1\n\t"
                "global_load_dwordx4 %2, %9, off offset:2048 sc0 sc1\n\t"
                "global_load_dwordx4 %3, %9, off offset:3072 sc0 sc1\n\t"
                "global_load_dwordx4 %4, %10, off sc0 sc1\n\t"
                "global_load_dwordx4 %5, %10, off offset:1024 sc0 sc1\n\t"
                "global_load_dwordx4 %6, %10, off offset:2048 sc0 sc1\n\t"
                "global_load_dwordx4 %7, %10, off offset:3072 sc0 sc1\n\t"
                "global_load_dword   %8, %11, off sc0 sc1\n\t"
                "s_waitcnt vmcnt(0)"
                : "=&v"(xv[0]), "=&v"(xv[1]), "=&v"(xv[2]), "=&v"(xv[3]),
                  "=&v"(xv[4]), "=&v"(xv[5]), "=&v"(xv[6]), "=&v"(xv[7]),
                  "=&v"(xp)
                : "v"(xb0), "v"(xb1), "v"(xq) : "memory");
            __builtin_amdgcn_sched_barrier(0);
        } else {
#pragma unroll
            for (int c = 0; c < 8; ++c)
                xv[c] = make_float4(0.f, 0.f, 0.f, 0.f);
        }

        // ---- matvec: W from AGPRs (read+fma), 4 independent chains ----
#pragma unroll
        for (int c = 0; c < 8; ++c) {
#pragma unroll
            for (int m = 0; m < RPW; ++m) {
                float t0, t1, t2, t3;
                AGPR_R(t0, a_w[m][c * 4 + 0]);
                AGPR_R(t1, a_w[m][c * 4 + 1]);
                AGPR_R(t2, a_w[m][c * 4 + 2]);
                AGPR_R(t3, a_w[m][c * 4 + 3]);
                float p0 = fmaf(t0, xv[c].x, acc[m]);
                float p1 = t1 * xv[c].y;
                float p2 = fmaf(t2, xv[c].z, p0);
                float p3 = fmaf(t3, xv[c].w, p1);
                acc[m] = p2 + p3;
            }
        }
#pragma unroll
        for (int m = 0; m < RPW; ++m) {
            float a = acc[m];
#pragma unroll
            for (int off = 32; off > 0; off >>= 1)
                a += __shfl_xor(a, off, 64);
            acc[m] = a;   // all lanes hold all 4 row sums
        }

        // ---- finish 4 rows (lanes 0..3): coherent store, then tag ----
        const int sw = t & 1;
        if (lane < RPW) {
            float pre = (lane == 0) ? acc[0]
                      : (lane == 1) ? acc[1]
                      : (lane == 2) ? acc[2] : acc[3];
            float xn  = 0.1f * xp + 0.9f * erf_approx(pre) * invs;
            st_coh_f32(out + (size_t)t * RSIZE + r0 + lane, xn);
        }
        if (t + 1 < T_STEPS) {
            asm volatile("s_waitcnt vmcnt(0)" ::: "memory");  // drain stores
            if (lane == 0)
                st_coh_u32(tags + sw * NWAVE + wid, (unsigned)(t + 1));
        }
    }
}

extern "C" void kernel_launch(void* const* d_in, const int* in_sizes, int n_in,
                              void* d_out, int out_size, void* d_ws,
                              size_t ws_size, hipStream_t stream) {
    const float* input = (const float*)d_in[0];
    const float* W_in  = (const float*)d_in[1];
    const float* W_res = (const float*)d_in[2];
    float*       out   = (float*)d_out;
    unsigned*    tags  = (unsigned*)d_ws;   // 2*512*4 = 4 KB (proven size)

    // tags must be zero at the start of every call (deterministic)
    hipMemsetAsync(tags, 0, 4096, stream);

    void* args[] = {(void*)&input, (void*)&W_in, (void*)&W_res,
                    (void*)&out, (void*)&tags};
    hipError_t err = hipLaunchCooperativeKernel(
        (const void*)esn_persistent, dim3(NBLK), dim3(NTHR), args, 0, stream);
    if (err != hipSuccess) {
        // 64 blocks / 256 CUs: trivially co-resident; plain launch fallback
        esn_persistent<<<dim3(NBLK), dim3(NTHR), 0, stream>>>(
            input, W_in, W_res, out, tags);
    }
}

// Round 10
// 130051.477 us; speedup vs baseline: 1.2456x; 1.2456x over previous
//
#include <hip/hip_runtime.h>
#include <math.h>

#define T_STEPS 20000
#define RSIZE   2048
#define ISIZE   128
#define NBLK    64
#define NTHR    512                    // 8 waves/block, 1 block/CU
#define WPB     (NTHR / 64)            // 8 waves per block
#define RPW     4                      // rows per wave

// ---- cheap erf: Abramowitz-Stegun 7.1.26, |err| <= 1.5e-7 (abs) ----
__device__ __forceinline__ float erf_approx(float x) {
    float ax = fabsf(x);
    float t  = 1.0f / (1.0f + 0.3275911f * ax);
    float y  = t * (0.254829592f +
               t * (-0.284496736f +
               t * (1.421413741f +
               t * (-1.453152027f +
               t * 1.061405429f))));
    float e  = __expf(-ax * ax);
    float r  = 1.0f - y * e;
    return copysignf(r, x);
}

// ---- AGPR parking (gfx950 unified RF; no MFMA here, AGPRs = free storage).
// VALU cannot source AGPRs on gfx950 — only v_accvgpr_read/write move data.
#define AGPR_W(a, v) asm volatile("v_accvgpr_write_b32 %0, %1" : "=a"(a) : "v"(v))
#define AGPR_R(v, a) asm volatile("v_accvgpr_read_b32 %0, %1" : "=v"(v) : "a"(a))

// ---- device-coherent (L3-serviced) accesses: no cache-wide fences needed ----
__device__ __forceinline__ unsigned ld_coh_u32(const unsigned* p) {
    unsigned r;
    asm volatile("global_load_dword %0, %1, off sc0 sc1\n\ts_waitcnt vmcnt(0)"
                 : "=&v"(r) : "v"(p) : "memory");
    return r;
}
__device__ __forceinline__ float4 ld_coh_f4(const float* p) {
    float4 r;
    asm volatile("global_load_dwordx4 %0, %1, off sc0 sc1\n\ts_waitcnt vmcnt(0)"
                 : "=&v"(r) : "v"(p) : "memory");
    return r;
}
__device__ __forceinline__ void st_coh_f32(float* p, float v) {
    asm volatile("global_store_dword %0, %1, off sc0 sc1"
                 :: "v"(p), "v"(v) : "memory");
}
__device__ __forceinline__ void st_coh_u32(unsigned* p, unsigned v) {
    asm volatile("global_store_dword %0, %1, off sc0 sc1"
                 :: "v"(p), "v"(v) : "memory");
}

__global__ __launch_bounds__(NTHR, 2) void esn_persistent(
        const float* __restrict__ input,   // [T, 128]
        const float* __restrict__ W_in,    // [2048, 128]
        const float* __restrict__ W_res,   // [2048, 2048]
        float* __restrict__ out,           // [T, 2048] (rows ARE the states)
        unsigned* __restrict__ flags) {    // [8 replicas][64] packed flags
    __shared__ float xbuf[RSIZE];
    __shared__ unsigned cnt;               // monotonic wave-completion counter

    const int tid  = threadIdx.x;
    const int lane = tid & 63;
    const int wv   = tid >> 6;
    const int wid  = blockIdx.x * WPB + wv;
    const int r0   = wid * RPW;
    const float invs = 0.022097086912079608f;  // 1/sqrt(2048)

    // ---- load W once, park in AGPRs (row r0+m, lane l: cols c*256+l*4..+3) --
    float a_w[RPW][32];
    float a_wi[RPW][2];
#pragma unroll
    for (int m = 0; m < RPW; ++m) {
        const float* row = W_res + (size_t)(r0 + m) * RSIZE;
#pragma unroll
        for (int c = 0; c < 8; ++c) {
            float4 w = *(const float4*)(row + c * 256 + lane * 4);
            AGPR_W(a_w[m][c * 4 + 0], w.x);
            AGPR_W(a_w[m][c * 4 + 1], w.y);
            AGPR_W(a_w[m][c * 4 + 2], w.z);
            AGPR_W(a_w[m][c * 4 + 3], w.w);
        }
        float2 wiv = *(const float2*)(W_in + (size_t)(r0 + m) * ISIZE + lane * 2);
        AGPR_W(a_wi[m][0], wiv.x);
        AGPR_W(a_wi[m][1], wiv.y);
    }
    if (tid == 0) cnt = 0;
    __syncthreads();

    for (int t = 0; t < T_STEPS; ++t) {
        // ---- input projection (independent of other blocks) ----
        float2 uv = ((const float2*)(input + (size_t)t * ISIZE))[lane];
        float acc[RPW];
#pragma unroll
        for (int m = 0; m < RPW; ++m) {
            float w0, w1;
            AGPR_R(w0, a_wi[m][0]);
            AGPR_R(w1, a_wi[m][1]);
            acc[m] = fmaf(w0, uv.x, w1 * uv.y);
        }

        // ---- wait (each wave polls its own packed replica), stage own slice -
        if (t > 0) {
            const unsigned want = (unsigned)t;
            const unsigned* pf = flags + wv * NBLK + lane;  // 256B, 2 lines
            while (true) {
                unsigned f = ld_coh_u32(pf);
                if (__all((int)(f >= want))) break;
                __builtin_amdgcn_s_sleep(1);
            }
            // flags at L3 => producers' coherent data stores are at L3;
            // our sc0 sc1 loads are L3-serviced => fresh.
            const float* xprev = out + (size_t)(t - 1) * RSIZE;
            ((float4*)xbuf)[tid] = ld_coh_f4(xprev + tid * 4);
        } else {
            ((float4*)xbuf)[tid] = make_float4(0.f, 0.f, 0.f, 0.f);
        }
        __syncthreads();   // the ONLY barrier per step: slices complete

        // ---- frags from LDS ----
        float4 xv[8];
#pragma unroll
        for (int c = 0; c < 8; ++c)
            xv[c] = ((const float4*)xbuf)[c * 64 + lane];
        float xp = xbuf[r0 + (lane & 3)];

        // ---- matvec: W from AGPRs (read+fma), 4 independent chains ----
#pragma unroll
        for (int c = 0; c < 8; ++c) {
#pragma unroll
            for (int m = 0; m < RPW; ++m) {
                float t0, t1, t2, t3;
                AGPR_R(t0, a_w[m][c * 4 + 0]);
                AGPR_R(t1, a_w[m][c * 4 + 1]);
                AGPR_R(t2, a_w[m][c * 4 + 2]);
                AGPR_R(t3, a_w[m][c * 4 + 3]);
                float p0 = fmaf(t0, xv[c].x, acc[m]);
                float p1 = t1 * xv[c].y;
                float p2 = fmaf(t2, xv[c].z, p0);
                float p3 = fmaf(t3, xv[c].w, p1);
                acc[m] = p2 + p3;
            }
        }
#pragma unroll
        for (int m = 0; m < RPW; ++m) {
            float a = acc[m];
#pragma unroll
            for (int off = 32; off > 0; off >>= 1)
                a += __shfl_xor(a, off, 64);
            acc[m] = a;   // all lanes hold all 4 row sums
        }

        // ---- finish 4 rows (lanes 0..3): coherent store ----
        if (lane < RPW) {
            float pre = (lane == 0) ? acc[0]
                      : (lane == 1) ? acc[1]
                      : (lane == 2) ? acc[2] : acc[3];
            float xn  = 0.1f * xp + 0.9f * erf_approx(pre) * invs;
            st_coh_f32(out + (size_t)t * RSIZE + r0 + lane, xn);
        }

        // ---- publish without a block barrier: drain own stores, then the
        // 8th wave to bump the LDS counter writes all 8 flag replicas.
        // (Also guards xbuf overwrite: publication implies every wave passed
        // its post-read atomic, so no step-t reads remain.)
        if (t + 1 < T_STEPS) {
            asm volatile("s_waitcnt vmcnt(0)" ::: "memory");
            if (lane == 0) {
                unsigned ret = __hip_atomic_fetch_add(&cnt, 1u, __ATOMIC_ACQ_REL,
                                                      __HIP_MEMORY_SCOPE_WORKGROUP);
                if (ret == 8u * (unsigned)t + 7u) {
#pragma unroll
                    for (int w = 0; w < WPB; ++w)
                        st_coh_u32(flags + w * NBLK + blockIdx.x,
                                   (unsigned)(t + 1));
                }
            }
        }
    }
}

extern "C" void kernel_launch(void* const* d_in, const int* in_sizes, int n_in,
                              void* d_out, int out_size, void* d_ws,
                              size_t ws_size, hipStream_t stream) {
    const float* input = (const float*)d_in[0];
    const float* W_in  = (const float*)d_in[1];
    const float* W_res = (const float*)d_in[2];
    float*       out   = (float*)d_out;
    unsigned*    flags = (unsigned*)d_ws;   // 8 replicas * 64 * 4B = 2 KB

    // flags must be zero at the start of every call (deterministic)
    hipMemsetAsync(flags, 0, WPB * NBLK * sizeof(unsigned), stream);

    void* args[] = {(void*)&input, (void*)&W_in, (void*)&W_res,
                    (void*)&out, (void*)&flags};
    hipError_t err = hipLaunchCooperativeKernel(
        (const void*)esn_persistent, dim3(NBLK), dim3(NTHR), args, 0, stream);
    if (err != hipSuccess) {
        // 64 blocks / 256 CUs: trivially co-resident; plain launch fallback
        esn_persistent<<<dim3(NBLK), dim3(NTHR), 0, stream>>>(
            input, W_in, W_res, out, flags);
    }
}

// Round 11
// 71490.680 us; speedup vs baseline: 2.2659x; 1.8191x over previous
//
#include <hip/hip_runtime.h>
#include <math.h>

#define T_STEPS 20000
#define RSIZE   2048
#define ISIZE   128
#define NBLK    64
#define NTHR    512                    // 8 waves/block, 1 block/CU
#define WPB     (NTHR / 64)            // 8 waves per block
#define RPW     4                      // rows per wave

// ---- cheap erf: Abramowitz-Stegun 7.1.26, |err| <= 1.5e-7 (abs) ----
__device__ __forceinline__ float erf_approx(float x) {
    float ax = fabsf(x);
    float t  = 1.0f / (1.0f + 0.3275911f * ax);
    float y  = t * (0.254829592f +
               t * (-0.284496736f +
               t * (1.421413741f +
               t * (-1.453152027f +
               t * 1.061405429f))));
    float e  = __expf(-ax * ax);
    float r  = 1.0f - y * e;
    return copysignf(r, x);
}

// ---- AGPR parking (gfx950 unified RF; no MFMA here, AGPRs = free storage).
// VALU cannot source AGPRs on gfx950 — only v_accvgpr_read/write move data.
#define AGPR_W(a, v) asm volatile("v_accvgpr_write_b32 %0, %1" : "=a"(a) : "v"(v))
#define AGPR_R(v, a) asm volatile("v_accvgpr_read_b32 %0, %1" : "=v"(v) : "a"(a))

// Single-instruction (value, epoch) publish — 8B aligned, one L3 transaction:
// tag and value cannot tear. Device-coherent (sc0 sc1), serviced at L3.
__device__ __forceinline__ void st_coh_pair(unsigned* p, unsigned lo, unsigned hi) {
    uint2 v; v.x = lo; v.y = hi;
    asm volatile("global_store_dwordx2 %0, %1, off sc0 sc1"
                 :: "v"(p), "v"(v) : "memory");
}

__global__ __launch_bounds__(NTHR, 2) void esn_persistent(
        const float* __restrict__ input,   // [T, 128]
        const float* __restrict__ W_in,    // [2048, 128]
        const float* __restrict__ W_res,   // [2048, 2048]
        float* __restrict__ out,           // [T, 2048] final outputs (plain)
        unsigned* __restrict__ X) {        // [2][2048][2] (value,epoch) pairs
    __shared__ float xbuf[2][RSIZE];       // LDS double buffer for x[t-1]

    const int tid  = threadIdx.x;
    const int lane = tid & 63;
    const int wv   = tid >> 6;
    const int wid  = blockIdx.x * WPB + wv;
    const int r0   = wid * RPW;
    const float invs = 0.022097086912079608f;  // 1/sqrt(2048)

    // ---- load W once, park in AGPRs (row r0+m, lane l: cols c*256+l*4..+3) --
    float a_w[RPW][32];
    float a_wi[RPW][2];
#pragma unroll
    for (int m = 0; m < RPW; ++m) {
        const float* row = W_res + (size_t)(r0 + m) * RSIZE;
#pragma unroll
        for (int c = 0; c < 8; ++c) {
            float4 w = *(const float4*)(row + c * 256 + lane * 4);
            AGPR_W(a_w[m][c * 4 + 0], w.x);
            AGPR_W(a_w[m][c * 4 + 1], w.y);
            AGPR_W(a_w[m][c * 4 + 2], w.z);
            AGPR_W(a_w[m][c * 4 + 3], w.w);
        }
        float2 wiv = *(const float2*)(W_in + (size_t)(r0 + m) * ISIZE + lane * 2);
        AGPR_W(a_wi[m][0], wiv.x);
        AGPR_W(a_wi[m][1], wiv.y);
    }

    for (int t = 0; t < T_STEPS; ++t) {
        // ---- input projection (independent of other blocks) ----
        float2 uv = ((const float2*)(input + (size_t)t * ISIZE))[lane];
        float acc[RPW];
#pragma unroll
        for (int m = 0; m < RPW; ++m) {
            float w0, w1;
            AGPR_R(w0, a_wi[m][0]);
            AGPR_R(w1, a_wi[m][1]);
            acc[m] = fmaf(w0, uv.x, w1 * uv.y);
        }

        // ---- acquire x[t-1]: poll own 4 (value,epoch) pairs — the poll IS
        // the stage (one L3 round trip, no flags, no producer drain) ----
        float4 myx;
        if (t > 0) {
            const int s = (t - 1) & 1;
            const unsigned want = (unsigned)t;
            const unsigned* pb = X + ((size_t)s * RSIZE + tid * 4) * 2;
            uint4 p0, p1;
            while (true) {
                asm volatile(
                    "global_load_dwordx4 %0, %2, off sc0 sc1\n\t"
                    "global_load_dwordx4 %1, %2, off offset:16 sc0 sc1\n\t"
                    "s_waitcnt vmcnt(0)"
                    : "=&v"(p0), "=&v"(p1) : "v"(pb) : "memory");
                __builtin_amdgcn_sched_barrier(0);
                if (p0.y == want && p0.w == want &&
                    p1.y == want && p1.w == want) break;   // per-lane exit
                __builtin_amdgcn_s_sleep(1);
            }
            myx = make_float4(__uint_as_float(p0.x), __uint_as_float(p0.z),
                              __uint_as_float(p1.x), __uint_as_float(p1.z));
        } else {
            myx = make_float4(0.f, 0.f, 0.f, 0.f);
        }
        float* xb = xbuf[t & 1];
        ((float4*)xb)[tid] = myx;
        __syncthreads();   // the ONLY barrier per step (LDS double-buffered)

        // ---- frags from LDS ----
        float4 xv[8];
#pragma unroll
        for (int c = 0; c < 8; ++c)
            xv[c] = ((const float4*)xb)[c * 64 + lane];
        float xp = xb[r0 + (lane & 3)];

        // ---- matvec: W from AGPRs (read+fma), 4 independent chains ----
#pragma unroll
        for (int c = 0; c < 8; ++c) {
#pragma unroll
            for (int m = 0; m < RPW; ++m) {
                float t0, t1, t2, t3;
                AGPR_R(t0, a_w[m][c * 4 + 0]);
                AGPR_R(t1, a_w[m][c * 4 + 1]);
                AGPR_R(t2, a_w[m][c * 4 + 2]);
                AGPR_R(t3, a_w[m][c * 4 + 3]);
                float p0 = fmaf(t0, xv[c].x, acc[m]);
                float p1 = t1 * xv[c].y;
                float p2 = fmaf(t2, xv[c].z, p0);
                float p3 = fmaf(t3, xv[c].w, p1);
                acc[m] = p2 + p3;
            }
        }
#pragma unroll
        for (int m = 0; m < RPW; ++m) {
            float a = acc[m];
#pragma unroll
            for (int off = 32; off > 0; off >>= 1)
                a += __shfl_xor(a, off, 64);
            acc[m] = a;   // all lanes hold all 4 row sums
        }

        // ---- finish 4 rows (lanes 0..3): output + self-announcing pair ----
        if (lane < RPW) {
            float pre = (lane == 0) ? acc[0]
                      : (lane == 1) ? acc[1]
                      : (lane == 2) ? acc[2] : acc[3];
            float xn  = 0.1f * xp + 0.9f * erf_approx(pre) * invs;
            out[(size_t)t * RSIZE + r0 + lane] = xn;          // plain cached
            st_coh_pair(X + ((size_t)(t & 1) * RSIZE + r0 + lane) * 2,
                        __float_as_uint(xn), (unsigned)(t + 1));
            // fire-and-forget: no drain, no flag, no barrier.
        }
    }
}

extern "C" void kernel_launch(void* const* d_in, const int* in_sizes, int n_in,
                              void* d_out, int out_size, void* d_ws,
                              size_t ws_size, hipStream_t stream) {
    const float* input = (const float*)d_in[0];
    const float* W_in  = (const float*)d_in[1];
    const float* W_res = (const float*)d_in[2];
    float*       out   = (float*)d_out;
    unsigned*    X     = (unsigned*)d_ws;   // 2*2048*8 B = 32 KB

    // epochs must be zero at the start of every call (replay leaves stale
    // tags that would spuriously match) — deterministic, on-stream.
    hipMemsetAsync(X, 0, 2 * RSIZE * 2 * sizeof(unsigned), stream);

    void* args[] = {(void*)&input, (void*)&W_in, (void*)&W_res,
                    (void*)&out, (void*)&X};
    hipError_t err = hipLaunchCooperativeKernel(
        (const void*)esn_persistent, dim3(NBLK), dim3(NTHR), args, 0, stream);
    if (err != hipSuccess) {
        // 64 blocks / 256 CUs: trivially co-resident; plain launch fallback
        esn_persistent<<<dim3(NBLK), dim3(NTHR), 0, stream>>>(
            input, W_in, W_res, out, X);
    }
}

// Round 12
// 62108.868 us; speedup vs baseline: 2.6081x; 1.1511x over previous
//
#include <hip/hip_runtime.h>
#include <math.h>

#define T_STEPS 20000
#define RSIZE   2048
#define ISIZE   128
#define NBLK    64
#define NTHR    512                    // 8 waves/block, 1 block/CU
#define WPB     (NTHR / 64)            // 8 waves per block
#define NWAVE   (NBLK * WPB)           // 512 waves
#define RPW     4                      // rows per wave

// ---- cheap erf: Abramowitz-Stegun 7.1.26, |err| <= 1.5e-7 (abs) ----
__device__ __forceinline__ float erf_approx(float x) {
    float ax = fabsf(x);
    float t  = 1.0f / (1.0f + 0.3275911f * ax);
    float y  = t * (0.254829592f +
               t * (-0.284496736f +
               t * (1.421413741f +
               t * (-1.453152027f +
               t * 1.061405429f))));
    float e  = __expf(-ax * ax);
    float r  = 1.0f - y * e;
    return copysignf(r, x);
}

// ---- AGPR parking (gfx950 unified RF; no MFMA here, AGPRs = free storage).
// VALU cannot source AGPRs on gfx950 — only v_accvgpr_read/write move data.
#define AGPR_W(a, v) asm volatile("v_accvgpr_write_b32 %0, %1" : "=a"(a) : "v"(v))
#define AGPR_R(v, a) asm volatile("v_accvgpr_read_b32 %0, %1" : "=v"(v) : "a"(a))

// ---- device-coherent (L3-serviced) accesses ----
__device__ __forceinline__ float4 ld_coh_f4(const float* p) {
    float4 r;
    asm volatile("global_load_dwordx4 %0, %1, off sc0 sc1\n\ts_waitcnt vmcnt(0)"
                 : "=&v"(r) : "v"(p) : "memory");
    return r;
}
__device__ __forceinline__ void st_coh_f32(float* p, float v) {
    asm volatile("global_store_dword %0, %1, off sc0 sc1"
                 :: "v"(p), "v"(v) : "memory");
}
__device__ __forceinline__ void st_coh_u32(unsigned* p, unsigned v) {
    asm volatile("global_store_dword %0, %1, off sc0 sc1"
                 :: "v"(p), "v"(v) : "memory");
}

__global__ __launch_bounds__(NTHR, 2) void esn_persistent(
        const float* __restrict__ input,   // [T, 128]
        const float* __restrict__ W_in,    // [2048, 128]
        const float* __restrict__ W_res,   // [2048, 2048]
        float* __restrict__ out,           // [T, 2048] (rows ARE the states)
        unsigned* __restrict__ flags) {    // [512] packed per-WAVE monotonic
    __shared__ float xbuf[RSIZE];

    const int tid  = threadIdx.x;
    const int lane = tid & 63;
    const int wv   = tid >> 6;
    const int wid  = blockIdx.x * WPB + wv;
    const int r0   = wid * RPW;
    const float invs = 0.022097086912079608f;  // 1/sqrt(2048)

    // ---- load W once, park in AGPRs (row r0+m, lane l: cols c*256+l*4..+3) --
    float a_w[RPW][32];
    float a_wi[RPW][2];
#pragma unroll
    for (int m = 0; m < RPW; ++m) {
        const float* row = W_res + (size_t)(r0 + m) * RSIZE;
#pragma unroll
        for (int c = 0; c < 8; ++c) {
            float4 w = *(const float4*)(row + c * 256 + lane * 4);
            AGPR_W(a_w[m][c * 4 + 0], w.x);
            AGPR_W(a_w[m][c * 4 + 1], w.y);
            AGPR_W(a_w[m][c * 4 + 2], w.z);
            AGPR_W(a_w[m][c * 4 + 3], w.w);
        }
        float2 wiv = *(const float2*)(W_in + (size_t)(r0 + m) * ISIZE + lane * 2);
        AGPR_W(a_wi[m][0], wiv.x);
        AGPR_W(a_wi[m][1], wiv.y);
    }

    // ---- software-pipelined input projection: base for step 0 ----
    float base[RPW];
    {
        float2 uv = ((const float2*)(input))[lane];
#pragma unroll
        for (int m = 0; m < RPW; ++m) {
            float w0, w1;
            AGPR_R(w0, a_wi[m][0]);
            AGPR_R(w1, a_wi[m][1]);
            base[m] = fmaf(w0, uv.x, w1 * uv.y);
        }
    }

    for (int t = 0; t < T_STEPS; ++t) {
        // ---- wait for x[t-1]: wave0 polls all 512 packed wave-flags ----
        if (t > 0) {
            if (wv == 0) {
                const unsigned want = (unsigned)t;
                const unsigned* pf = flags + lane * 8;
                uint4 g0, g1;
                while (true) {
                    asm volatile(
                        "global_load_dwordx4 %0, %2, off sc0 sc1\n\t"
                        "global_load_dwordx4 %1, %2, off offset:16 sc0 sc1\n\t"
                        "s_waitcnt vmcnt(0)"
                        : "=&v"(g0), "=&v"(g1) : "v"(pf) : "memory");
                    __builtin_amdgcn_sched_barrier(0);
                    bool ok = g0.x >= want && g0.y >= want &&
                              g0.z >= want && g0.w >= want &&
                              g1.x >= want && g1.y >= want &&
                              g1.z >= want && g1.w >= want;
                    if (__all((int)ok)) break;
                    __builtin_amdgcn_s_sleep(1);
                }
            }
            __syncthreads();
            // flags at L3 => producers' coherent value stores are at L3;
            // sc0 sc1 stage loads are L3-serviced => fresh.
            const float* xprev = out + (size_t)(t - 1) * RSIZE;
            ((float4*)xbuf)[tid] = ld_coh_f4(xprev + tid * 4);
        } else {
            ((float4*)xbuf)[tid] = make_float4(0.f, 0.f, 0.f, 0.f);
        }
        __syncthreads();

        // ---- frags from LDS ----
        float4 xv[8];
#pragma unroll
        for (int c = 0; c < 8; ++c)
            xv[c] = ((const float4*)xbuf)[c * 64 + lane];
        float xp = xbuf[r0 + (lane & 3)];

        // ---- matvec: W from AGPRs (read+fma), independent chains ----
        float acc[RPW];
#pragma unroll
        for (int m = 0; m < RPW; ++m) acc[m] = base[m];
#pragma unroll
        for (int c = 0; c < 8; ++c) {
#pragma unroll
            for (int m = 0; m < RPW; ++m) {
                float t0, t1, t2, t3;
                AGPR_R(t0, a_w[m][c * 4 + 0]);
                AGPR_R(t1, a_w[m][c * 4 + 1]);
                AGPR_R(t2, a_w[m][c * 4 + 2]);
                AGPR_R(t3, a_w[m][c * 4 + 3]);
                float p0 = fmaf(t0, xv[c].x, acc[m]);
                float p1 = t1 * xv[c].y;
                float p2 = fmaf(t2, xv[c].z, p0);
                float p3 = fmaf(t3, xv[c].w, p1);
                acc[m] = p2 + p3;
            }
        }
#pragma unroll
        for (int m = 0; m < RPW; ++m) {
            float a = acc[m];
#pragma unroll
            for (int off = 32; off > 0; off >>= 1)
                a += __shfl_xor(a, off, 64);
            acc[m] = a;   // all lanes hold all 4 row sums
        }

        // ---- finish 4 rows (lanes 0..3): coherent value stores ----
        if (lane < RPW) {
            float pre = (lane == 0) ? acc[0]
                      : (lane == 1) ? acc[1]
                      : (lane == 2) ? acc[2] : acc[3];
            float xn  = 0.1f * xp + 0.9f * erf_approx(pre) * invs;
            st_coh_f32(out + (size_t)t * RSIZE + r0 + lane, xn);
        }

        // ---- producer tail, per-wave (no block barrier):
        // overlap the store drain with step t+1's input projection,
        // then publish this wave's flag.
        if (t + 1 < T_STEPS) {
            float2 uv = ((const float2*)(input + (size_t)(t + 1) * ISIZE))[lane];
#pragma unroll
            for (int m = 0; m < RPW; ++m) {
                float w0, w1;
                AGPR_R(w0, a_wi[m][0]);
                AGPR_R(w1, a_wi[m][1]);
                base[m] = fmaf(w0, uv.x, w1 * uv.y);
            }
            asm volatile("s_waitcnt vmcnt(0)" ::: "memory");  // drain own stores
            if (lane == 0)
                st_coh_u32(flags + wid, (unsigned)(t + 1));
        }
    }
}

extern "C" void kernel_launch(void* const* d_in, const int* in_sizes, int n_in,
                              void* d_out, int out_size, void* d_ws,
                              size_t ws_size, hipStream_t stream) {
    const float* input = (const float*)d_in[0];
    const float* W_in  = (const float*)d_in[1];
    const float* W_res = (const float*)d_in[2];
    float*       out   = (float*)d_out;
    unsigned*    flags = (unsigned*)d_ws;   // 512 * 4 B = 2 KB packed

    // flags must be zero at the start of every call (deterministic)
    hipMemsetAsync(flags, 0, NWAVE * sizeof(unsigned), stream);

    void* args[] = {(void*)&input, (void*)&W_in, (void*)&W_res,
                    (void*)&out, (void*)&flags};
    hipError_t err = hipLaunchCooperativeKernel(
        (const void*)esn_persistent, dim3(NBLK), dim3(NTHR), args, 0, stream);
    if (err != hipSuccess) {
        // 64 blocks / 256 CUs: trivially co-resident; plain launch fallback
        esn_persistent<<<dim3(NBLK), dim3(NTHR), 0, stream>>>(
            input, W_in, W_res, out, flags);
    }
}